// Round 11
// baseline (322.041 us; speedup 1.0000x reference)
//
#include <hip/hip_runtime.h>
#include <hip/hip_bf16.h>
#include <math.h>

#define S_LEN 2048
#define H_DIM 2048
#define NH 16
#define Q_LORA 1536
#define KV_LORA 512
#define D_NOPE 128
#define D_ROPE 64
#define D_V 128
#define D_QK 192

typedef unsigned short ushort_t;
typedef __attribute__((ext_vector_type(8))) short short8;
typedef __attribute__((ext_vector_type(4))) float f32x4;

__device__ __forceinline__ ushort_t f2bf(float f) {
    unsigned int u = __float_as_uint(f);
    u = (u + 0x7FFFu + ((u >> 16) & 1u)) >> 16;
    return (ushort_t)u;
}
__device__ __forceinline__ float bf2f(ushort_t u) {
    return __uint_as_float(((unsigned int)u) << 16);
}

// raw v_exp_f32: computes 2^x (TRANS pipe)
__device__ __forceinline__ float exp2_fast(float x) {
    float r;
    asm volatile("v_exp_f32 %0, %1" : "=v"(r) : "v"(x));
    return r;
}

// packed f32x2 -> bf16x2 (RNE), single instruction; lo = src0
__device__ __forceinline__ unsigned cvt_pk_bf16(float lo, float hi) {
    unsigned r;
    asm volatile("v_cvt_pk_bf16_f32 %0, %1, %2" : "=v"(r) : "v"(lo), "v"(hi));
    return r;
}

__device__ __forceinline__ void storeC(float* p, float v) { *p = v; }
__device__ __forceinline__ void storeC(ushort_t* p, float v) { *p = f2bf(v); }

__device__ __forceinline__ void gload_lds16(const ushort_t* g, ushort_t* l) {
    __builtin_amdgcn_global_load_lds(
        (const __attribute__((address_space(1))) unsigned int*)(const void*)g,
        (__attribute__((address_space(3))) unsigned int*)(void*)l, 16, 0, 0);
}

// -------- unified conversion: hs f32->bf16 + 5 weight transposes, one launch --------
__device__ __forceinline__ void convT_body(
    const float* __restrict__ W, ushort_t* __restrict__ Wt,
    int K, int N, int n0, int k0, float (*tile)[33])
{
    const int tr = threadIdx.x >> 5, tc = threadIdx.x & 31;
    #pragma unroll
    for (int i = 0; i < 4; ++i) {
        int r = tr + i * 8;
        float v = 0.f;
        if (n0 + tc < N) v = W[(size_t)(k0 + r) * N + n0 + tc];
        tile[r][tc] = v;
    }
    __syncthreads();
    #pragma unroll
    for (int i = 0; i < 4; ++i) {
        int r = tr + i * 8;
        Wt[(size_t)(n0 + r) * K + k0 + tc] = f2bf(tile[tc][r]);
    }
}

__global__ __launch_bounds__(256) void unified_conv(
    const float* __restrict__ hs, ushort_t* __restrict__ hs16,
    const float* __restrict__ Wqa, const float* __restrict__ Wkva,
    const float* __restrict__ Wqb, const float* __restrict__ Wkvb,
    const float* __restrict__ Wo,
    ushort_t* __restrict__ WcatT, ushort_t* __restrict__ WqbT,
    ushort_t* __restrict__ WkvbT, ushort_t* __restrict__ WoT)
{
    __shared__ float tile[32][33];
    int b = blockIdx.x;
    if (b < 4096) {   // hs elementwise
        int base = (b * 256 + threadIdx.x) * 4;
        float4 v = *(const float4*)(hs + base);
        hs16[base + 0] = f2bf(v.x);
        hs16[base + 1] = f2bf(v.y);
        hs16[base + 2] = f2bf(v.z);
        hs16[base + 3] = f2bf(v.w);
        return;
    }
    b -= 4096;
    const float* W; ushort_t* Wt; int K, N, nbx;
    if (b < 3072)        {            W = Wqa;  Wt = WcatT;                              K = 2048; N = 1536; nbx = 48;  }
    else if (b < 4352)   { b -= 3072; W = Wkva; Wt = WcatT + (size_t)Q_LORA * H_DIM;     K = 2048; N = 576;  nbx = 20;  }
    else if (b < 8960)   { b -= 4352; W = Wqb;  Wt = WqbT;                               K = 1536; N = 3072; nbx = 96;  }
    else if (b < 11008)  { b -= 8960; W = Wkvb; Wt = WkvbT;                              K = 512;  N = 4096; nbx = 128; }
    else                 { b -= 11008; W = Wo;  Wt = WoT;                                K = 2048; N = 2048; nbx = 64;  }
    convT_body(W, Wt, K, N, (b % nbx) * 32, (b / nbx) * 32, tile);
}

// ------- fused: rmsnorm-q (blocks 0..2047) + rmsnorm-kv (2048..4095) + rope-k (4096..) -------
__global__ __launch_bounds__(256) void fused_norm_ropek(
    const ushort_t* __restrict__ cat16r, ushort_t* __restrict__ qa16,
    ushort_t* __restrict__ ckv16n, ushort_t* __restrict__ kpe16,
    const float* __restrict__ qlnw, const float* __restrict__ klnw)
{
    __shared__ float red[4];
    const int b = blockIdx.x;
    if (b < 4096) {
        const bool isQ = (b < 2048);
        const int row = isQ ? b : b - 2048;
        const int K = isQ ? Q_LORA : KV_LORA;
        const ushort_t* x = cat16r + (size_t)row * 2176 + (isQ ? 0 : Q_LORA);
        ushort_t* y = (isQ ? qa16 + (size_t)row * Q_LORA : ckv16n + (size_t)row * KV_LORA);
        const float* wv = isQ ? qlnw : klnw;
        float ss = 0.f;
        for (int i = threadIdx.x; i < K; i += 256) { float v = bf2f(x[i]); ss += v * v; }
        #pragma unroll
        for (int off = 32; off > 0; off >>= 1) ss += __shfl_down(ss, off);
        int lane = threadIdx.x & 63, wid = threadIdx.x >> 6;
        if (lane == 0) red[wid] = ss;
        __syncthreads();
        float tot = red[0] + red[1] + red[2] + red[3];
        float rs = rsqrtf(tot / (float)K + 1e-6f);
        for (int i = threadIdx.x; i < K; i += 256)
            y[i] = f2bf(bf2f(x[i]) * rs * wv[i]);
    } else {
        int idx = (b - 4096) * 256 + threadIdx.x;
        if (idx >= S_LEN * 32) return;
        int i = idx & 31;
        int s = idx >> 5;
        float inv = powf(10000.0f, -(2.0f * i) / 64.0f);
        float ang = (float)s * inv;
        float c = cosf(ang), sn = sinf(ang);
        const ushort_t* p = cat16r + (size_t)s * 2176 + Q_LORA + KV_LORA;
        ushort_t* q = kpe16 + (size_t)s * D_ROPE;
        float x1 = bf2f(p[i]), x2 = bf2f(p[i + 32]);
        q[i]      = f2bf(x1 * c - x2 * sn);
        q[i + 32] = f2bf(x2 * c + x1 * sn);
    }
}

// ---- GEMM body A8: 128x128 tile, EIGHT waves (512 thr), 2-DEEP counted-vmcnt
// pipeline, 64 KB LDS. Rationale: G2/G7 grids give 1 block/CU; with 4 waves
// that is 1 wave/SIMD (the round-8-attn death regime: every vmcnt/barrier/
// ds_read->MFMA chain fully exposed — measured ~4050 cy/K-step vs 770 LDS
// floor). 8 waves -> 2 waves/SIMD halves exposed latency at unchanged LDS
// footprint. Per-wave quadrant 32x64 (4M x 2N wave grid), acc[2][4];
// staging = 4 gload_lds16/thread/K-step -> pipeline waits at vmcnt(4). ----
template <typename CT>
__device__ __forceinline__ void gemm_body_128_w8(
    const ushort_t* __restrict__ A, const ushort_t* __restrict__ Bt,
    CT* __restrict__ C, int N, int K, int m0, int n0,
    ushort_t* Al, ushort_t* Bl)
{
    const int tid = threadIdx.x;           // 0..511
    const int lane = tid & 63;
    const int w = tid >> 6;                // 0..7
    const int lm = lane & 15, quad = lane >> 4;
    const int wm = w >> 1;                 // 0..3  (M quadrant, 32 rows)
    const int wn = w & 1;                  // 0..1  (N half, 64 cols)

    f32x4 acc[2][4];
    #pragma unroll
    for (int a = 0; a < 2; ++a)
        #pragma unroll
        for (int b = 0; b < 4; ++b) acc[a][b] = (f32x4){0.f, 0.f, 0.f, 0.f};

    const int rrow = tid >> 2;                                // 0..127
    const int rcsw = ((tid & 3) ^ ((tid >> 3) & 3)) * 8;      // swizzled source k-slot
    const int swq  = quad ^ ((lm >> 1) & 3);                  // swizzled read slot

    const int NT = K >> 6;

    auto stage = [&](int buf, int k0) {
        #pragma unroll
        for (int c = 0; c < 2; ++c) {
            gload_lds16(A + (size_t)(m0 + rrow) * K + k0 + c * 32 + rcsw,
                        Al + buf * 8192 + c * 4096 + tid * 8);
            gload_lds16(Bt + (size_t)(n0 + rrow) * K + k0 + c * 32 + rcsw,
                        Bl + buf * 8192 + c * 4096 + tid * 8);
        }
    };

    stage(0, 0);       // 4 loads/thread
    stage(1, 64);      // +4 (NT >= 2 for all our shapes)

    int cur = 0;
    for (int t = 0; t < NT; ++t) {
        if (t + 1 < NT) asm volatile("s_waitcnt vmcnt(4)" ::: "memory");
        else            asm volatile("s_waitcnt vmcnt(0)" ::: "memory");
        __builtin_amdgcn_s_barrier();
        __builtin_amdgcn_sched_barrier(0);

        const ushort_t* Ab = Al + cur * 8192;
        const ushort_t* Bb = Bl + cur * 8192;
        #pragma unroll
        for (int c = 0; c < 2; ++c) {
            short8 af[2], bf[4];
            #pragma unroll
            for (int t2 = 0; t2 < 2; ++t2)
                af[t2] = *(const short8*)(Ab + c * 4096 + (wm * 32 + t2 * 16 + lm) * 32 + swq * 8);
            #pragma unroll
            for (int t2 = 0; t2 < 4; ++t2)
                bf[t2] = *(const short8*)(Bb + c * 4096 + (wn * 64 + t2 * 16 + lm) * 32 + swq * 8);
            #pragma unroll
            for (int mt = 0; mt < 2; ++mt)
                #pragma unroll
                for (int nt = 0; nt < 4; ++nt)
                    acc[mt][nt] = __builtin_amdgcn_mfma_f32_16x16x32_bf16(
                        af[mt], bf[nt], acc[mt][nt], 0, 0, 0);
        }

        __builtin_amdgcn_s_barrier();
        __builtin_amdgcn_sched_barrier(0);
        if (t + 2 < NT) stage(cur, (t + 2) << 6);
        cur ^= 1;
    }

    #pragma unroll
    for (int mt = 0; mt < 2; ++mt)
        #pragma unroll
        for (int nt = 0; nt < 4; ++nt)
            #pragma unroll
            for (int r = 0; r < 4; ++r) {
                int row = m0 + wm * 32 + mt * 16 + quad * 4 + r;
                int col = n0 + wn * 64 + nt * 16 + lm;
                storeC(&C[(size_t)row * N + col], acc[mt][nt][r]);
            }
}

// ---- GEMM body B: 128x128 tile, 4 waves, SINGLE-buffer staging in Sh,
// epilogue scale; optional fused V-transpose epilogue (vtp != nullptr). ----
__device__ __forceinline__ void gemm_body_128_sb(
    const ushort_t* __restrict__ A, const ushort_t* __restrict__ Bt,
    ushort_t* __restrict__ C, int N, int K, int m0, int n0,
    ushort_t* Sh, float csc, ushort_t* vtp)
{
    ushort_t* Al = Sh;
    ushort_t* Bl = Sh + 8192;
    const int tid = threadIdx.x;
    const int lane = tid & 63;
    const int w = tid >> 6;
    const int lm = lane & 15, quad = lane >> 4;
    const int wr = w >> 1, wc = w & 1;

    f32x4 acc[4][4];
    #pragma unroll
    for (int a = 0; a < 4; ++a)
        #pragma unroll
        for (int b = 0; b < 4; ++b) acc[a][b] = (f32x4){0.f, 0.f, 0.f, 0.f};

    const int rrow = tid >> 2;
    const int rcsw = ((tid & 3) ^ ((tid >> 3) & 3)) * 8;
    const int swq  = quad ^ ((lm >> 1) & 3);

    for (int k0 = 0; k0 < K; k0 += 64) {
        __syncthreads();
        #pragma unroll
        for (int c = 0; c < 2; ++c)
            #pragma unroll
            for (int half = 0; half < 2; ++half) {
                gload_lds16(A + (size_t)(m0 + half * 64 + rrow) * K + k0 + c * 32 + rcsw,
                            Al + c * 4096 + half * 2048 + tid * 8);
                gload_lds16(Bt + (size_t)(n0 + half * 64 + rrow) * K + k0 + c * 32 + rcsw,
                            Bl + c * 4096 + half * 2048 + tid * 8);
            }
        __syncthreads();

        #pragma unroll
        for (int c = 0; c < 2; ++c) {
            short8 af[4], bf[4];
            #pragma unroll
            for (int t2 = 0; t2 < 4; ++t2)
                af[t2] = *(const short8*)(Al + c * 4096 + (wr * 64 + t2 * 16 + lm) * 32 + swq * 8);
            #pragma unroll
            for (int t2 = 0; t2 < 4; ++t2)
                bf[t2] = *(const short8*)(Bl + c * 4096 + (wc * 64 + t2 * 16 + lm) * 32 + swq * 8);
            #pragma unroll
            for (int mt = 0; mt < 4; ++mt)
                #pragma unroll
                for (int nt = 0; nt < 4; ++nt)
                    acc[mt][nt] = __builtin_amdgcn_mfma_f32_16x16x32_bf16(
                        af[mt], bf[nt], acc[mt][nt], 0, 0, 0);
        }
    }

    if (vtp) {
        #pragma unroll
        for (int hv = 0; hv < 2; ++hv) {
            __syncthreads();
            if (wc == hv) {
                #pragma unroll
                for (int mt = 0; mt < 4; ++mt)
                    #pragma unroll
                    for (int nt = 0; nt < 4; ++nt)
                        #pragma unroll
                        for (int r = 0; r < 4; ++r)
                            Sh[(nt * 16 + lm) * 136 + wr * 64 + mt * 16 + quad * 4 + r] =
                                f2bf(acc[mt][nt][r]);
            }
            __syncthreads();
            const int dv = tid >> 2;
            const int sc_ = (tid & 3) * 32;
            ushort_t* dst = vtp + (size_t)(hv * 64 + dv) * S_LEN + m0 + sc_;
            const ushort_t* src = Sh + dv * 136 + sc_;
            #pragma unroll
            for (int u = 0; u < 4; ++u)
                *(short8*)(dst + u * 8) = *(const short8*)(src + u * 8);
        }
        return;
    }

    #pragma unroll
    for (int mt = 0; mt < 4; ++mt)
        #pragma unroll
        for (int nt = 0; nt < 4; ++nt)
            #pragma unroll
            for (int r = 0; r < 4; ++r) {
                int row = m0 + wr * 64 + mt * 16 + quad * 4 + r;
                int col = n0 + wc * 64 + nt * 16 + lm;
                storeC(&C[(size_t)row * N + col], acc[mt][nt][r] * csc);
            }
}

template <typename CT>
__global__ __launch_bounds__(512) void mfma_gemm_bt(
    const ushort_t* __restrict__ A, const ushort_t* __restrict__ Bt,
    CT* __restrict__ C, int N, int K)
{
    __shared__ ushort_t Al[2 * 8192];
    __shared__ ushort_t Bl[2 * 8192];
    gemm_body_128_w8<CT>(A, Bt, C, N, K, blockIdx.y * 128, blockIdx.x * 128, Al, Bl);
}

// grouped: GEMM4a (qbuf, scaled) + GEMM4b (kv, with fused V^T epilogue on odd col-tiles)
__global__ __launch_bounds__(256) void mfma_gemm_dual(
    const ushort_t* __restrict__ A1, const ushort_t* __restrict__ Bt1,
    ushort_t* __restrict__ C1, int N1, int K1, int nb1, float sc1,
    const ushort_t* __restrict__ A2, const ushort_t* __restrict__ Bt2,
    ushort_t* __restrict__ C2, int N2, int K2, ushort_t* __restrict__ v16t)
{
    __shared__ ushort_t Sh[16384];
    int g = blockIdx.x;
    if (g < nb1) {
        int nbx = N1 / 128;
        gemm_body_128_sb(A1, Bt1, C1, N1, K1, (g / nbx) * 128, (g % nbx) * 128, Sh, sc1, nullptr);
    } else {
        g -= nb1;
        int nbx = N2 / 128;   // 32
        int mt = g / nbx, nt = g % nbx;
        ushort_t* vtp = nullptr;
        if (nt & 1) {
            int h = nt >> 1;
            vtp = v16t + (size_t)h * D_V * S_LEN;
        }
        gemm_body_128_sb(A2, Bt2, C2, N2, K2, mt * 128, nt * 128, Sh, 1.0f, vtp);
    }
}

// ---- SWAPPED-OPERAND online softmax (T12 layout; validated R10) ----
// s[st][r] = score(key = k0+st*16+quad*4+r, qrow = qw+lm). Each lane owns one
// q-row; row reduce = in-lane fmax + 2 shfl_xor; P packed via cvt_pk (keys
// adjacent) -> 8 ds_write_b32. Ps row stride 76 ushorts (38 dwords -> 16
// distinct banks for the b32 writes; was 36 -> 4-way alias, 811K conflicts).
template <bool MASKED>
__device__ __forceinline__ void softmax_swapped(
    f32x4 s[4], int k0, int qw, int lm, int quad,
    float& m_, float& l_, f32x4 O[8], ushort_t* ps)
{
    float a[4][4];
    #pragma unroll
    for (int st = 0; st < 4; ++st)
        #pragma unroll
        for (int r = 0; r < 4; ++r) {
            float v = s[st][r];
            if (MASKED) v = (k0 + st * 16 + quad * 4 + r <= qw + lm) ? v : -1e30f;
            a[st][r] = v;
        }
    float mx = a[0][0];
    #pragma unroll
    for (int st = 0; st < 4; ++st)
        #pragma unroll
        for (int r = 0; r < 4; ++r) mx = fmaxf(mx, a[st][r]);
    mx = fmaxf(mx, __shfl_xor(mx, 16));
    mx = fmaxf(mx, __shfl_xor(mx, 32));

    unsigned* prow = (unsigned*)(ps + lm * 76);
    if (__all(mx - m_ <= 11.5f)) {
        float lsum = 0.f;
        #pragma unroll
        for (int st = 0; st < 4; ++st) {
            float p0 = exp2_fast(a[st][0] - m_);
            float p1 = exp2_fast(a[st][1] - m_);
            float p2 = exp2_fast(a[st][2] - m_);
            float p3 = exp2_fast(a[st][3] - m_);
            lsum += (p0 + p1) + (p2 + p3);
            prow[(st * 16 + quad * 4) >> 1]       = cvt_pk_bf16(p0, p1);
            prow[((st * 16 + quad * 4) >> 1) + 1] = cvt_pk_bf16(p2, p3);
        }
        lsum += __shfl_xor(lsum, 16);
        lsum += __shfl_xor(lsum, 32);
        l_ += lsum;
    } else {
        float mn = fmaxf(m_, mx);
        float alpha = exp2_fast(m_ - mn);
        float lsum = 0.f;
        #pragma unroll
        for (int st = 0; st < 4; ++st) {
            float p0 = exp2_fast(a[st][0] - mn);
            float p1 = exp2_fast(a[st][1] - mn);
            float p2 = exp2_fast(a[st][2] - mn);
            float p3 = exp2_fast(a[st][3] - mn);
            lsum += (p0 + p1) + (p2 + p3);
            prow[(st * 16 + quad * 4) >> 1]       = cvt_pk_bf16(p0, p1);
            prow[((st * 16 + quad * 4) >> 1) + 1] = cvt_pk_bf16(p2, p3);
        }
        lsum += __shfl_xor(lsum, 16);
        lsum += __shfl_xor(lsum, 32);
        l_ = l_ * alpha + lsum;
        m_ = mn;
        #pragma unroll
        for (int c = 0; c < 8; ++c) O[c] *= alpha;
    }
}

// ---- MFMA flash attention: R10 kernel (swapped operands, lane-local softmax,
// R5 pipeline skeleton, balanced paired grid) with Ps stride 72 -> 76. ----
__global__ __launch_bounds__(256) void mla_attn_kernel(
    const ushort_t* __restrict__ qb, const ushort_t* __restrict__ kvb,
    const ushort_t* __restrict__ kpe, const ushort_t* __restrict__ v16t,
    ushort_t* __restrict__ aout16)
{
    __shared__ ushort_t Kn[2 * 4 * 64 * 32];   // 32 KB (2 bufs)
    __shared__ ushort_t Kr[2 * 2 * 64 * 32];   // 16 KB (2 bufs)
    __shared__ ushort_t Vt[2 * 128 * 32];      // 16 KB (single buf)
    __shared__ ushort_t Ps[4][16 * 76];        //  9.5 KB

    const int o = blockIdx.x;
    const int h = o & 15;
    const int oy = o >> 4;                       // dispatch-order tile slot 0..31
    const int ty = (oy < 16) ? oy : 47 - oy;     // balanced pairing: ty + ty' = 31
    const int q0 = 64 * (31 - ty);               // heavy-first within first round
    const int w = threadIdx.x >> 6;              // 0..3
    const int lane = threadIdx.x & 63;
    const int lm = lane & 15, quad = lane >> 4;
    const int qw = q0 + 16 * w;
    ushort_t* myPs = Ps[w];

    const int skey = lane >> 2;                               // 0..15
    const int ssw  = ((lane & 3) ^ ((lane >> 3) & 3)) * 8;    // swizzled source slot
    const int swq  = quad ^ ((lm >> 1) & 3);                  // swizzled read slot

    // Q fragments (pre-scaled by 192^-0.5*log2e in the Wqb GEMM epilogue)
    // + fused RoPE on chunks 4/5 (rotation commutes with the scaling)
    short8 qf[6];
    #pragma unroll
    for (int f = 0; f < 6; ++f)
        qf[f] = *(const short8*)(qb + (size_t)(qw + lm) * 3072 + h * 192 + f * 32 + quad * 8);
    {
        float srow = (float)(qw + lm);
        #pragma unroll
        for (int j = 0; j < 8; ++j) {
            int i = quad * 8 + j;
            float inv = powf(10000.0f, -(2.0f * i) / 64.0f);
            float ang = srow * inv;
            float c = cosf(ang), sn = sinf(ang);
            float x1 = bf2f((ushort_t)qf[4][j]);
            float x2 = bf2f((ushort_t)qf[5][j]);
            qf[4][j] = (short)f2bf(x1 * c - x2 * sn);
            qf[5][j] = (short)f2bf(x2 * c + x1 * sn);
        }
    }
    // drain Q loads so vmcnt bookkeeping below is exact
    asm volatile("s_waitcnt vmcnt(0)" ::: "memory");

    f32x4 O[8];
    #pragma unroll
    for (int c = 0; c < 8; ++c) O[c] = (f32x4){0.f, 0.f, 0.f, 0.f};
    float m_ = -1e30f;
    float l_ = 0.f;

    // per-wave staging: Kn 4 loads, Kr 2 loads, V 4 loads
    auto stageK = [&](int buf, int k0s) {
        #pragma unroll
        for (int i = 0; i < 4; ++i)
            gload_lds16(kvb + (size_t)(k0s + i * 16 + skey) * 4096 + h * 256 + w * 32 + ssw,
                        Kn + buf * 8192 + w * 2048 + i * 512 + lane * 8);
        #pragma unroll
        for (int ii = 0; ii < 2; ++ii) {
            int i = 2 * (w & 1) + ii;
            gload_lds16(kpe + (size_t)(k0s + i * 16 + skey) * 64 + (w >> 1) * 32 + ssw,
                        Kr + buf * 4096 + (w >> 1) * 2048 + i * 512 + lane * 8);
        }
    };
    auto stageV = [&](int k0s) {
        #pragma unroll
        for (int jj = 0; jj < 4; ++jj) {
            int j = 4 * (w >> 1) + jj;
            gload_lds16(v16t + ((size_t)h * 128 + j * 16 + skey) * S_LEN + k0s + (w & 1) * 32 + ssw,
                        Vt + (w & 1) * 4096 + j * 512 + lane * 8);
        }
    };

    const int nt = q0 / 64 + 1;
    stageK(0, 0);   // 6 outstanding/wave

    for (int t = 0; t < nt; ++t) {
        const int k0 = t * 64;
        const bool hasNext = (t + 1 < nt);
        const int kb = t & 1;

        stageV(k0);                                // +4
        if (hasNext) stageK(kb ^ 1, k0 + 64);      // +6

        if (hasNext) asm volatile("s_waitcnt vmcnt(10)" ::: "memory");  // K(t) landed
        else         asm volatile("s_waitcnt vmcnt(4)"  ::: "memory");
        __builtin_amdgcn_s_barrier();
        __builtin_amdgcn_sched_barrier(0);

        // ---- QK^T (SWAPPED: A = K fragment, B = Q fragment) ----
        f32x4 s[4];
        #pragma unroll
        for (int st = 0; st < 4; ++st) s[st] = (f32x4){0.f, 0.f, 0.f, 0.f};
        #pragma unroll
        for (int f = 0; f < 4; ++f)
            #pragma unroll
            for (int st = 0; st < 4; ++st) {
                short8 kf = *(const short8*)(Kn + kb * 8192 + f * 2048 + (st * 16 + lm) * 32 + swq * 8);
                s[st] = __builtin_amdgcn_mfma_f32_16x16x32_bf16(kf, qf[f], s[st], 0, 0, 0);
            }
        #pragma unroll
        for (int f2 = 0; f2 < 2; ++f2)
            #pragma unroll
            for (int st = 0; st < 4; ++st) {
                short8 kf = *(const short8*)(Kr + kb * 4096 + f2 * 2048 + (st * 16 + lm) * 32 + swq * 8);
                s[st] = __builtin_amdgcn_mfma_f32_16x16x32_bf16(kf, qf[4 + f2], s[st], 0, 0, 0);
            }

        if (k0 + 63 <= qw) softmax_swapped<false>(s, k0, qw, lm, quad, m_, l_, O, myPs);
        else               softmax_swapped<true >(s, k0, qw, lm, quad, m_, l_, O, myPs);

        // V(t) landed (K(t+1) still in flight) + own Ps writes visible
        if (hasNext) asm volatile("s_waitcnt vmcnt(6) lgkmcnt(0)" ::: "memory");
        else         asm volatile("s_waitcnt vmcnt(0) lgkmcnt(0)" ::: "memory");
        __builtin_amdgcn_s_barrier();
        __builtin_amdgcn_sched_barrier(0);

        // ---- PV (SWAPPED: A = V^T fragment, B = P fragment) ----
        short8 pf0 = *(const short8*)(myPs + lm * 76 + quad * 8);
        short8 pf1 = *(const short8*)(myPs + lm * 76 + 32 + quad * 8);
        #pragma unroll
        for (int c = 0; c < 8; ++c) {
            short8 vf0 = *(const short8*)(Vt + (c * 16 + lm) * 32 + swq * 8);
            short8 vf1 = *(const short8*)(Vt + 4096 + (c * 16 + lm) * 32 + swq * 8);
            O[c] = __builtin_amdgcn_mfma_f32_16x16x32_bf16(vf0, pf0, O[c], 0, 0, 0);
            O[c] = __builtin_amdgcn_mfma_f32_16x16x32_bf16(vf1, pf1, O[c], 0, 0, 0);
        }

        __builtin_amdgcn_s_barrier();   // release Vt and Kn/Kr[kb] for next iter's staging
        __builtin_amdgcn_sched_barrier(0);
    }

    // epilogue: per-lane scalar l; packed dword stores (dv-adjacent pairs)
    float linv = __builtin_amdgcn_rcpf(l_);
    const size_t rb = (size_t)(qw + lm) * 2048 + h * D_V + quad * 4;
    #pragma unroll
    for (int c = 0; c < 8; ++c) {
        *(unsigned*)(aout16 + rb + c * 16)     = cvt_pk_bf16(O[c][0] * linv, O[c][1] * linv);
        *(unsigned*)(aout16 + rb + c * 16 + 2) = cvt_pk_bf16(O[c][2] * linv, O[c][3] * linv);
    }
}

extern "C" void kernel_launch(void* const* d_in, const int* in_sizes, int n_in,
                              void* d_out, int out_size, void* d_ws, size_t ws_size,
                              hipStream_t stream)
{
    (void)in_sizes; (void)n_in; (void)out_size; (void)ws_size;
    const float* hs   = (const float*)d_in[0];
    const float* Wqa  = (const float*)d_in[1];
    const float* qlnw = (const float*)d_in[2];
    const float* Wqb  = (const float*)d_in[3];
    const float* Wkva = (const float*)d_in[4];
    const float* klnw = (const float*)d_in[5];
    const float* Wkvb = (const float*)d_in[6];
    const float* Wo   = (const float*)d_in[7];
    float* out = (float*)d_out;

    ushort_t* p = (ushort_t*)d_ws;
    ushort_t* hs16   = p; p += (size_t)S_LEN * H_DIM;
    ushort_t* WcatT  = p; p += (size_t)2176 * H_DIM;     // [Wqa^T 1536 ; Wkva^T 640] x 2048
    ushort_t* WqbT   = p; p += (size_t)3072 * Q_LORA;
    ushort_t* WkvbT  = p; p += (size_t)4096 * KV_LORA;
    ushort_t* WoT    = p; p += (size_t)H_DIM * H_DIM;
    ushort_t* cat16r = p; p += (size_t)S_LEN * 2176;     // [qa_raw | ckv_raw | kpe_raw | pad]
    ushort_t* qa16   = p; p += (size_t)S_LEN * Q_LORA;
    ushort_t* qbuf16 = p; p += (size_t)S_LEN * 3072;
    ushort_t* ckv16n = p; p += (size_t)S_LEN * KV_LORA;
    ushort_t* kpe16  = p; p += (size_t)S_LEN * D_ROPE;
    ushort_t* kv16   = p; p += (size_t)S_LEN * 4096;
    ushort_t* v16t   = p; p += (size_t)NH * D_V * S_LEN;
    ushort_t* aout16 = p; p += (size_t)S_LEN * 2048;

    // 192^-0.5 * log2(e): attention scale + exp->exp2 folded into q projection
    const float QSCALE = 0.0721687836f * 1.44269504f;

    // 1. all conversions in one launch (hs + 5 weight transposes)
    unified_conv<<<19200, 256, 0, stream>>>(
        hs, hs16, Wqa, Wkva, Wqb, Wkvb, Wo, WcatT, WqbT, WkvbT, WoT);
    // 2. cat16r = hs16 @ WcatT^T  [2048 x 2176, K=2048]  — 8-wave blocks
    mfma_gemm_bt<ushort_t><<<dim3(2176 / 128, S_LEN / 128), 512, 0, stream>>>(
        hs16, WcatT, cat16r, 2176, H_DIM);
    // 3. fused rmsnorm-q / rmsnorm-kv / rope-k
    fused_norm_ropek<<<4096 + 256, 256, 0, stream>>>(cat16r, qa16, ckv16n, kpe16, qlnw, klnw);
    // 4. grouped GEMM: qbuf16 (pre-scaled) + kv16 with fused V-transpose epilogue
    mfma_gemm_dual<<<384 + 512, 256, 0, stream>>>(
        qa16, WqbT, qbuf16, 3072, Q_LORA, 384, QSCALE,
        ckv16n, WkvbT, kv16, 4096, KV_LORA, v16t);
    // 5. attention (swapped-operand lane-local softmax; R5 pipeline skeleton)
    mla_attn_kernel<<<512, 256, 0, stream>>>(qbuf16, kv16, kpe16, v16t, aout16);
    // 6. out = aout16 @ WoT^T [2048 x 2048, K=2048], fp32 store — 8-wave blocks
    mfma_gemm_bt<float><<<dim3(H_DIM / 128, S_LEN / 128), 512, 0, stream>>>(
        aout16, WoT, out, H_DIM, H_DIM);
}

// Round 12
// 314.727 us; speedup vs baseline: 1.0232x; 1.0232x over previous
//
#include <hip/hip_runtime.h>
#include <hip/hip_bf16.h>
#include <math.h>

#define S_LEN 2048
#define H_DIM 2048
#define NH 16
#define Q_LORA 1536
#define KV_LORA 512
#define D_NOPE 128
#define D_ROPE 64
#define D_V 128
#define D_QK 192

typedef unsigned short ushort_t;
typedef __attribute__((ext_vector_type(8))) short short8;
typedef __attribute__((ext_vector_type(4))) float f32x4;

__device__ __forceinline__ ushort_t f2bf(float f) {
    unsigned int u = __float_as_uint(f);
    u = (u + 0x7FFFu + ((u >> 16) & 1u)) >> 16;
    return (ushort_t)u;
}
__device__ __forceinline__ float bf2f(ushort_t u) {
    return __uint_as_float(((unsigned int)u) << 16);
}

// raw v_exp_f32: computes 2^x (TRANS pipe)
__device__ __forceinline__ float exp2_fast(float x) {
    float r;
    asm volatile("v_exp_f32 %0, %1" : "=v"(r) : "v"(x));
    return r;
}

// packed f32x2 -> bf16x2 (RNE), single instruction; lo = src0
__device__ __forceinline__ unsigned cvt_pk_bf16(float lo, float hi) {
    unsigned r;
    asm volatile("v_cvt_pk_bf16_f32 %0, %1, %2" : "=v"(r) : "v"(lo), "v"(hi));
    return r;
}

__device__ __forceinline__ void storeC(float* p, float v) { *p = v; }
__device__ __forceinline__ void storeC(ushort_t* p, float v) { *p = f2bf(v); }

__device__ __forceinline__ void gload_lds16(const ushort_t* g, ushort_t* l) {
    __builtin_amdgcn_global_load_lds(
        (const __attribute__((address_space(1))) unsigned int*)(const void*)g,
        (__attribute__((address_space(3))) unsigned int*)(void*)l, 16, 0, 0);
}

// -------- unified conversion: hs f32->bf16 + 5 weight transposes, one launch --------
__device__ __forceinline__ void convT_body(
    const float* __restrict__ W, ushort_t* __restrict__ Wt,
    int K, int N, int n0, int k0, float (*tile)[33])
{
    const int tr = threadIdx.x >> 5, tc = threadIdx.x & 31;
    #pragma unroll
    for (int i = 0; i < 4; ++i) {
        int r = tr + i * 8;
        float v = 0.f;
        if (n0 + tc < N) v = W[(size_t)(k0 + r) * N + n0 + tc];
        tile[r][tc] = v;
    }
    __syncthreads();
    #pragma unroll
    for (int i = 0; i < 4; ++i) {
        int r = tr + i * 8;
        Wt[(size_t)(n0 + r) * K + k0 + tc] = f2bf(tile[tc][r]);
    }
}

__global__ __launch_bounds__(256) void unified_conv(
    const float* __restrict__ hs, ushort_t* __restrict__ hs16,
    const float* __restrict__ Wqa, const float* __restrict__ Wkva,
    const float* __restrict__ Wqb, const float* __restrict__ Wkvb,
    const float* __restrict__ Wo,
    ushort_t* __restrict__ WcatT, ushort_t* __restrict__ WqbT,
    ushort_t* __restrict__ WkvbT, ushort_t* __restrict__ WoT)
{
    __shared__ float tile[32][33];
    int b = blockIdx.x;
    if (b < 4096) {   // hs elementwise
        int base = (b * 256 + threadIdx.x) * 4;
        float4 v = *(const float4*)(hs + base);
        hs16[base + 0] = f2bf(v.x);
        hs16[base + 1] = f2bf(v.y);
        hs16[base + 2] = f2bf(v.z);
        hs16[base + 3] = f2bf(v.w);
        return;
    }
    b -= 4096;
    const float* W; ushort_t* Wt; int K, N, nbx;
    if (b < 3072)        {            W = Wqa;  Wt = WcatT;                              K = 2048; N = 1536; nbx = 48;  }
    else if (b < 4352)   { b -= 3072; W = Wkva; Wt = WcatT + (size_t)Q_LORA * H_DIM;     K = 2048; N = 576;  nbx = 20;  }
    else if (b < 8960)   { b -= 4352; W = Wqb;  Wt = WqbT;                               K = 1536; N = 3072; nbx = 96;  }
    else if (b < 11008)  { b -= 8960; W = Wkvb; Wt = WkvbT;                              K = 512;  N = 4096; nbx = 128; }
    else                 { b -= 11008; W = Wo;  Wt = WoT;                                K = 2048; N = 2048; nbx = 64;  }
    convT_body(W, Wt, K, N, (b % nbx) * 32, (b / nbx) * 32, tile);
}

// ------- fused: rmsnorm-q (blocks 0..2047) + rmsnorm-kv (2048..4095) + rope-k (4096..) -------
__global__ __launch_bounds__(256) void fused_norm_ropek(
    const ushort_t* __restrict__ cat16r, ushort_t* __restrict__ qa16,
    ushort_t* __restrict__ ckv16n, ushort_t* __restrict__ kpe16,
    const float* __restrict__ qlnw, const float* __restrict__ klnw)
{
    __shared__ float red[4];
    const int b = blockIdx.x;
    if (b < 4096) {
        const bool isQ = (b < 2048);
        const int row = isQ ? b : b - 2048;
        const int K = isQ ? Q_LORA : KV_LORA;
        const ushort_t* x = cat16r + (size_t)row * 2176 + (isQ ? 0 : Q_LORA);
        ushort_t* y = (isQ ? qa16 + (size_t)row * Q_LORA : ckv16n + (size_t)row * KV_LORA);
        const float* wv = isQ ? qlnw : klnw;
        float ss = 0.f;
        for (int i = threadIdx.x; i < K; i += 256) { float v = bf2f(x[i]); ss += v * v; }
        #pragma unroll
        for (int off = 32; off > 0; off >>= 1) ss += __shfl_down(ss, off);
        int lane = threadIdx.x & 63, wid = threadIdx.x >> 6;
        if (lane == 0) red[wid] = ss;
        __syncthreads();
        float tot = red[0] + red[1] + red[2] + red[3];
        float rs = rsqrtf(tot / (float)K + 1e-6f);
        for (int i = threadIdx.x; i < K; i += 256)
            y[i] = f2bf(bf2f(x[i]) * rs * wv[i]);
    } else {
        int idx = (b - 4096) * 256 + threadIdx.x;
        if (idx >= S_LEN * 32) return;
        int i = idx & 31;
        int s = idx >> 5;
        float inv = powf(10000.0f, -(2.0f * i) / 64.0f);
        float ang = (float)s * inv;
        float c = cosf(ang), sn = sinf(ang);
        const ushort_t* p = cat16r + (size_t)s * 2176 + Q_LORA + KV_LORA;
        ushort_t* q = kpe16 + (size_t)s * D_ROPE;
        float x1 = bf2f(p[i]), x2 = bf2f(p[i + 32]);
        q[i]      = f2bf(x1 * c - x2 * sn);
        q[i + 32] = f2bf(x2 * c + x1 * sn);
    }
}

// ---- GEMM body A8: 128x128 tile, EIGHT waves (512 thr), 2-DEEP counted-vmcnt
// pipeline, 64 KB LDS (R11, kept: +4 µs on the 1-block/CU GEMMs). ----
template <typename CT>
__device__ __forceinline__ void gemm_body_128_w8(
    const ushort_t* __restrict__ A, const ushort_t* __restrict__ Bt,
    CT* __restrict__ C, int N, int K, int m0, int n0,
    ushort_t* Al, ushort_t* Bl)
{
    const int tid = threadIdx.x;           // 0..511
    const int lane = tid & 63;
    const int w = tid >> 6;                // 0..7
    const int lm = lane & 15, quad = lane >> 4;
    const int wm = w >> 1;                 // 0..3  (M quadrant, 32 rows)
    const int wn = w & 1;                  // 0..1  (N half, 64 cols)

    f32x4 acc[2][4];
    #pragma unroll
    for (int a = 0; a < 2; ++a)
        #pragma unroll
        for (int b = 0; b < 4; ++b) acc[a][b] = (f32x4){0.f, 0.f, 0.f, 0.f};

    const int rrow = tid >> 2;                                // 0..127
    const int rcsw = ((tid & 3) ^ ((tid >> 3) & 3)) * 8;      // swizzled source k-slot
    const int swq  = quad ^ ((lm >> 1) & 3);                  // swizzled read slot

    const int NT = K >> 6;

    auto stage = [&](int buf, int k0) {
        #pragma unroll
        for (int c = 0; c < 2; ++c) {
            gload_lds16(A + (size_t)(m0 + rrow) * K + k0 + c * 32 + rcsw,
                        Al + buf * 8192 + c * 4096 + tid * 8);
            gload_lds16(Bt + (size_t)(n0 + rrow) * K + k0 + c * 32 + rcsw,
                        Bl + buf * 8192 + c * 4096 + tid * 8);
        }
    };

    stage(0, 0);       // 4 loads/thread
    stage(1, 64);      // +4

    int cur = 0;
    for (int t = 0; t < NT; ++t) {
        if (t + 1 < NT) asm volatile("s_waitcnt vmcnt(4)" ::: "memory");
        else            asm volatile("s_waitcnt vmcnt(0)" ::: "memory");
        __builtin_amdgcn_s_barrier();
        __builtin_amdgcn_sched_barrier(0);

        const ushort_t* Ab = Al + cur * 8192;
        const ushort_t* Bb = Bl + cur * 8192;
        #pragma unroll
        for (int c = 0; c < 2; ++c) {
            short8 af[2], bf[4];
            #pragma unroll
            for (int t2 = 0; t2 < 2; ++t2)
                af[t2] = *(const short8*)(Ab + c * 4096 + (wm * 32 + t2 * 16 + lm) * 32 + swq * 8);
            #pragma unroll
            for (int t2 = 0; t2 < 4; ++t2)
                bf[t2] = *(const short8*)(Bb + c * 4096 + (wn * 64 + t2 * 16 + lm) * 32 + swq * 8);
            #pragma unroll
            for (int mt = 0; mt < 2; ++mt)
                #pragma unroll
                for (int nt = 0; nt < 4; ++nt)
                    acc[mt][nt] = __builtin_amdgcn_mfma_f32_16x16x32_bf16(
                        af[mt], bf[nt], acc[mt][nt], 0, 0, 0);
        }

        __builtin_amdgcn_s_barrier();
        __builtin_amdgcn_sched_barrier(0);
        if (t + 2 < NT) stage(cur, (t + 2) << 6);
        cur ^= 1;
    }

    #pragma unroll
    for (int mt = 0; mt < 2; ++mt)
        #pragma unroll
        for (int nt = 0; nt < 4; ++nt)
            #pragma unroll
            for (int r = 0; r < 4; ++r) {
                int row = m0 + wm * 32 + mt * 16 + quad * 4 + r;
                int col = n0 + wn * 64 + nt * 16 + lm;
                storeC(&C[(size_t)row * N + col], acc[mt][nt][r]);
            }
}

// ---- GEMM body B: 128x128 tile, 4 waves, SINGLE-buffer staging in Sh,
// epilogue scale; optional fused V-transpose epilogue (vtp != nullptr). ----
__device__ __forceinline__ void gemm_body_128_sb(
    const ushort_t* __restrict__ A, const ushort_t* __restrict__ Bt,
    ushort_t* __restrict__ C, int N, int K, int m0, int n0,
    ushort_t* Sh, float csc, ushort_t* vtp)
{
    ushort_t* Al = Sh;
    ushort_t* Bl = Sh + 8192;
    const int tid = threadIdx.x;
    const int lane = tid & 63;
    const int w = tid >> 6;
    const int lm = lane & 15, quad = lane >> 4;
    const int wr = w >> 1, wc = w & 1;

    f32x4 acc[4][4];
    #pragma unroll
    for (int a = 0; a < 4; ++a)
        #pragma unroll
        for (int b = 0; b < 4; ++b) acc[a][b] = (f32x4){0.f, 0.f, 0.f, 0.f};

    const int rrow = tid >> 2;
    const int rcsw = ((tid & 3) ^ ((tid >> 3) & 3)) * 8;
    const int swq  = quad ^ ((lm >> 1) & 3);

    for (int k0 = 0; k0 < K; k0 += 64) {
        __syncthreads();
        #pragma unroll
        for (int c = 0; c < 2; ++c)
            #pragma unroll
            for (int half = 0; half < 2; ++half) {
                gload_lds16(A + (size_t)(m0 + half * 64 + rrow) * K + k0 + c * 32 + rcsw,
                            Al + c * 4096 + half * 2048 + tid * 8);
                gload_lds16(Bt + (size_t)(n0 + half * 64 + rrow) * K + k0 + c * 32 + rcsw,
                            Bl + c * 4096 + half * 2048 + tid * 8);
            }
        __syncthreads();

        #pragma unroll
        for (int c = 0; c < 2; ++c) {
            short8 af[4], bf[4];
            #pragma unroll
            for (int t2 = 0; t2 < 4; ++t2)
                af[t2] = *(const short8*)(Al + c * 4096 + (wr * 64 + t2 * 16 + lm) * 32 + swq * 8);
            #pragma unroll
            for (int t2 = 0; t2 < 4; ++t2)
                bf[t2] = *(const short8*)(Bl + c * 4096 + (wc * 64 + t2 * 16 + lm) * 32 + swq * 8);
            #pragma unroll
            for (int mt = 0; mt < 4; ++mt)
                #pragma unroll
                for (int nt = 0; nt < 4; ++nt)
                    acc[mt][nt] = __builtin_amdgcn_mfma_f32_16x16x32_bf16(
                        af[mt], bf[nt], acc[mt][nt], 0, 0, 0);
        }
    }

    if (vtp) {
        #pragma unroll
        for (int hv = 0; hv < 2; ++hv) {
            __syncthreads();
            if (wc == hv) {
                #pragma unroll
                for (int mt = 0; mt < 4; ++mt)
                    #pragma unroll
                    for (int nt = 0; nt < 4; ++nt)
                        #pragma unroll
                        for (int r = 0; r < 4; ++r)
                            Sh[(nt * 16 + lm) * 136 + wr * 64 + mt * 16 + quad * 4 + r] =
                                f2bf(acc[mt][nt][r]);
            }
            __syncthreads();
            const int dv = tid >> 2;
            const int sc_ = (tid & 3) * 32;
            ushort_t* dst = vtp + (size_t)(hv * 64 + dv) * S_LEN + m0 + sc_;
            const ushort_t* src = Sh + dv * 136 + sc_;
            #pragma unroll
            for (int u = 0; u < 4; ++u)
                *(short8*)(dst + u * 8) = *(const short8*)(src + u * 8);
        }
        return;
    }

    #pragma unroll
    for (int mt = 0; mt < 4; ++mt)
        #pragma unroll
        for (int nt = 0; nt < 4; ++nt)
            #pragma unroll
            for (int r = 0; r < 4; ++r) {
                int row = m0 + wr * 64 + mt * 16 + quad * 4 + r;
                int col = n0 + wc * 64 + nt * 16 + lm;
                storeC(&C[(size_t)row * N + col], acc[mt][nt][r] * csc);
            }
}

template <typename CT>
__global__ __launch_bounds__(512) void mfma_gemm_bt(
    const ushort_t* __restrict__ A, const ushort_t* __restrict__ Bt,
    CT* __restrict__ C, int N, int K)
{
    __shared__ ushort_t Al[2 * 8192];
    __shared__ ushort_t Bl[2 * 8192];
    gemm_body_128_w8<CT>(A, Bt, C, N, K, blockIdx.y * 128, blockIdx.x * 128, Al, Bl);
}

// grouped: GEMM4a (qbuf, scaled) + GEMM4b (kv, with fused V^T epilogue on odd col-tiles)
__global__ __launch_bounds__(256) void mfma_gemm_dual(
    const ushort_t* __restrict__ A1, const ushort_t* __restrict__ Bt1,
    ushort_t* __restrict__ C1, int N1, int K1, int nb1, float sc1,
    const ushort_t* __restrict__ A2, const ushort_t* __restrict__ Bt2,
    ushort_t* __restrict__ C2, int N2, int K2, ushort_t* __restrict__ v16t)
{
    __shared__ ushort_t Sh[16384];
    int g = blockIdx.x;
    if (g < nb1) {
        int nbx = N1 / 128;
        gemm_body_128_sb(A1, Bt1, C1, N1, K1, (g / nbx) * 128, (g % nbx) * 128, Sh, sc1, nullptr);
    } else {
        g -= nb1;
        int nbx = N2 / 128;   // 32
        int mt = g / nbx, nt = g % nbx;
        ushort_t* vtp = nullptr;
        if (nt & 1) {
            int h = nt >> 1;
            vtp = v16t + (size_t)h * D_V * S_LEN;
        }
        gemm_body_128_sb(A2, Bt2, C2, N2, K2, mt * 128, nt * 128, Sh, 1.0f, vtp);
    }
}

// ---- SWAPPED-OPERAND online softmax (T12 layout; R10 exact, stride 72:
// 144 B = 16B-aligned ds_read_b128 on the PV side — the R11 stride-76 pad
// misaligned those reads and regressed; write-side b32 aliasing stays). ----
template <bool MASKED>
__device__ __forceinline__ void softmax_swapped(
    f32x4 s[4], int k0, int qw, int lm, int quad,
    float& m_, float& l_, f32x4 O[8], ushort_t* ps)
{
    float a[4][4];
    #pragma unroll
    for (int st = 0; st < 4; ++st)
        #pragma unroll
        for (int r = 0; r < 4; ++r) {
            float v = s[st][r];
            if (MASKED) v = (k0 + st * 16 + quad * 4 + r <= qw + lm) ? v : -1e30f;
            a[st][r] = v;
        }
    float mx = a[0][0];
    #pragma unroll
    for (int st = 0; st < 4; ++st)
        #pragma unroll
        for (int r = 0; r < 4; ++r) mx = fmaxf(mx, a[st][r]);
    mx = fmaxf(mx, __shfl_xor(mx, 16));
    mx = fmaxf(mx, __shfl_xor(mx, 32));

    unsigned* prow = (unsigned*)(ps + lm * 72);
    if (__all(mx - m_ <= 11.5f)) {
        float lsum = 0.f;
        #pragma unroll
        for (int st = 0; st < 4; ++st) {
            float p0 = exp2_fast(a[st][0] - m_);
            float p1 = exp2_fast(a[st][1] - m_);
            float p2 = exp2_fast(a[st][2] - m_);
            float p3 = exp2_fast(a[st][3] - m_);
            lsum += (p0 + p1) + (p2 + p3);
            prow[(st * 16 + quad * 4) >> 1]       = cvt_pk_bf16(p0, p1);
            prow[((st * 16 + quad * 4) >> 1) + 1] = cvt_pk_bf16(p2, p3);
        }
        lsum += __shfl_xor(lsum, 16);
        lsum += __shfl_xor(lsum, 32);
        l_ += lsum;
    } else {
        float mn = fmaxf(m_, mx);
        float alpha = exp2_fast(m_ - mn);
        float lsum = 0.f;
        #pragma unroll
        for (int st = 0; st < 4; ++st) {
            float p0 = exp2_fast(a[st][0] - mn);
            float p1 = exp2_fast(a[st][1] - mn);
            float p2 = exp2_fast(a[st][2] - mn);
            float p3 = exp2_fast(a[st][3] - mn);
            lsum += (p0 + p1) + (p2 + p3);
            prow[(st * 16 + quad * 4) >> 1]       = cvt_pk_bf16(p0, p1);
            prow[((st * 16 + quad * 4) >> 1) + 1] = cvt_pk_bf16(p2, p3);
        }
        lsum += __shfl_xor(lsum, 16);
        lsum += __shfl_xor(lsum, 32);
        l_ = l_ * alpha + lsum;
        m_ = mn;
        #pragma unroll
        for (int c = 0; c < 8; ++c) O[c] *= alpha;
    }
}

// ---- MFMA flash attention: R10 kernel EXACT (best measured, 74.7 µs).
// Swapped operands, lane-local softmax, R5 split-staging counted-vmcnt
// pipeline, balanced paired grid, Ps stride 72. ----
__global__ __launch_bounds__(256) void mla_attn_kernel(
    const ushort_t* __restrict__ qb, const ushort_t* __restrict__ kvb,
    const ushort_t* __restrict__ kpe, const ushort_t* __restrict__ v16t,
    ushort_t* __restrict__ aout16)
{
    __shared__ ushort_t Kn[2 * 4 * 64 * 32];   // 32 KB (2 bufs)
    __shared__ ushort_t Kr[2 * 2 * 64 * 32];   // 16 KB (2 bufs)
    __shared__ ushort_t Vt[2 * 128 * 32];      // 16 KB (single buf)
    __shared__ ushort_t Ps[4][16 * 72];        //  9 KB

    const int o = blockIdx.x;
    const int h = o & 15;
    const int oy = o >> 4;                       // dispatch-order tile slot 0..31
    const int ty = (oy < 16) ? oy : 47 - oy;     // balanced pairing: ty + ty' = 31
    const int q0 = 64 * (31 - ty);               // heavy-first within first round
    const int w = threadIdx.x >> 6;              // 0..3
    const int lane = threadIdx.x & 63;
    const int lm = lane & 15, quad = lane >> 4;
    const int qw = q0 + 16 * w;
    ushort_t* myPs = Ps[w];

    const int skey = lane >> 2;                               // 0..15
    const int ssw  = ((lane & 3) ^ ((lane >> 3) & 3)) * 8;    // swizzled source slot
    const int swq  = quad ^ ((lm >> 1) & 3);                  // swizzled read slot

    // Q fragments (pre-scaled by 192^-0.5*log2e in the Wqb GEMM epilogue)
    // + fused RoPE on chunks 4/5 (rotation commutes with the scaling)
    short8 qf[6];
    #pragma unroll
    for (int f = 0; f < 6; ++f)
        qf[f] = *(const short8*)(qb + (size_t)(qw + lm) * 3072 + h * 192 + f * 32 + quad * 8);
    {
        float srow = (float)(qw + lm);
        #pragma unroll
        for (int j = 0; j < 8; ++j) {
            int i = quad * 8 + j;
            float inv = powf(10000.0f, -(2.0f * i) / 64.0f);
            float ang = srow * inv;
            float c = cosf(ang), sn = sinf(ang);
            float x1 = bf2f((ushort_t)qf[4][j]);
            float x2 = bf2f((ushort_t)qf[5][j]);
            qf[4][j] = (short)f2bf(x1 * c - x2 * sn);
            qf[5][j] = (short)f2bf(x2 * c + x1 * sn);
        }
    }
    // drain Q loads so vmcnt bookkeeping below is exact
    asm volatile("s_waitcnt vmcnt(0)" ::: "memory");

    f32x4 O[8];
    #pragma unroll
    for (int c = 0; c < 8; ++c) O[c] = (f32x4){0.f, 0.f, 0.f, 0.f};
    float m_ = -1e30f;
    float l_ = 0.f;

    // per-wave staging: Kn 4 loads, Kr 2 loads, V 4 loads
    auto stageK = [&](int buf, int k0s) {
        #pragma unroll
        for (int i = 0; i < 4; ++i)
            gload_lds16(kvb + (size_t)(k0s + i * 16 + skey) * 4096 + h * 256 + w * 32 + ssw,
                        Kn + buf * 8192 + w * 2048 + i * 512 + lane * 8);
        #pragma unroll
        for (int ii = 0; ii < 2; ++ii) {
            int i = 2 * (w & 1) + ii;
            gload_lds16(kpe + (size_t)(k0s + i * 16 + skey) * 64 + (w >> 1) * 32 + ssw,
                        Kr + buf * 4096 + (w >> 1) * 2048 + i * 512 + lane * 8);
        }
    };
    auto stageV = [&](int k0s) {
        #pragma unroll
        for (int jj = 0; jj < 4; ++jj) {
            int j = 4 * (w >> 1) + jj;
            gload_lds16(v16t + ((size_t)h * 128 + j * 16 + skey) * S_LEN + k0s + (w & 1) * 32 + ssw,
                        Vt + (w & 1) * 4096 + j * 512 + lane * 8);
        }
    };

    const int nt = q0 / 64 + 1;
    stageK(0, 0);   // 6 outstanding/wave

    for (int t = 0; t < nt; ++t) {
        const int k0 = t * 64;
        const bool hasNext = (t + 1 < nt);
        const int kb = t & 1;

        stageV(k0);                                // +4
        if (hasNext) stageK(kb ^ 1, k0 + 64);      // +6

        if (hasNext) asm volatile("s_waitcnt vmcnt(10)" ::: "memory");  // K(t) landed
        else         asm volatile("s_waitcnt vmcnt(4)"  ::: "memory");
        __builtin_amdgcn_s_barrier();
        __builtin_amdgcn_sched_barrier(0);

        // ---- QK^T (SWAPPED: A = K fragment, B = Q fragment) ----
        f32x4 s[4];
        #pragma unroll
        for (int st = 0; st < 4; ++st) s[st] = (f32x4){0.f, 0.f, 0.f, 0.f};
        #pragma unroll
        for (int f = 0; f < 4; ++f)
            #pragma unroll
            for (int st = 0; st < 4; ++st) {
                short8 kf = *(const short8*)(Kn + kb * 8192 + f * 2048 + (st * 16 + lm) * 32 + swq * 8);
                s[st] = __builtin_amdgcn_mfma_f32_16x16x32_bf16(kf, qf[f], s[st], 0, 0, 0);
            }
        #pragma unroll
        for (int f2 = 0; f2 < 2; ++f2)
            #pragma unroll
            for (int st = 0; st < 4; ++st) {
                short8 kf = *(const short8*)(Kr + kb * 4096 + f2 * 2048 + (st * 16 + lm) * 32 + swq * 8);
                s[st] = __builtin_amdgcn_mfma_f32_16x16x32_bf16(kf, qf[4 + f2], s[st], 0, 0, 0);
            }

        if (k0 + 63 <= qw) softmax_swapped<false>(s, k0, qw, lm, quad, m_, l_, O, myPs);
        else               softmax_swapped<true >(s, k0, qw, lm, quad, m_, l_, O, myPs);

        // V(t) landed (K(t+1) still in flight) + own Ps writes visible
        if (hasNext) asm volatile("s_waitcnt vmcnt(6) lgkmcnt(0)" ::: "memory");
        else         asm volatile("s_waitcnt vmcnt(0) lgkmcnt(0)" ::: "memory");
        __builtin_amdgcn_s_barrier();
        __builtin_amdgcn_sched_barrier(0);

        // ---- PV (SWAPPED: A = V^T fragment, B = P fragment) ----
        short8 pf0 = *(const short8*)(myPs + lm * 72 + quad * 8);
        short8 pf1 = *(const short8*)(myPs + lm * 72 + 32 + quad * 8);
        #pragma unroll
        for (int c = 0; c < 8; ++c) {
            short8 vf0 = *(const short8*)(Vt + (c * 16 + lm) * 32 + swq * 8);
            short8 vf1 = *(const short8*)(Vt + 4096 + (c * 16 + lm) * 32 + swq * 8);
            O[c] = __builtin_amdgcn_mfma_f32_16x16x32_bf16(vf0, pf0, O[c], 0, 0, 0);
            O[c] = __builtin_amdgcn_mfma_f32_16x16x32_bf16(vf1, pf1, O[c], 0, 0, 0);
        }

        __builtin_amdgcn_s_barrier();   // release Vt and Kn/Kr[kb] for next iter's staging
        __builtin_amdgcn_sched_barrier(0);
    }

    // epilogue: per-lane scalar l; packed dword stores (dv-adjacent pairs)
    float linv = __builtin_amdgcn_rcpf(l_);
    const size_t rb = (size_t)(qw + lm) * 2048 + h * D_V + quad * 4;
    #pragma unroll
    for (int c = 0; c < 8; ++c) {
        *(unsigned*)(aout16 + rb + c * 16)     = cvt_pk_bf16(O[c][0] * linv, O[c][1] * linv);
        *(unsigned*)(aout16 + rb + c * 16 + 2) = cvt_pk_bf16(O[c][2] * linv, O[c][3] * linv);
    }
}

extern "C" void kernel_launch(void* const* d_in, const int* in_sizes, int n_in,
                              void* d_out, int out_size, void* d_ws, size_t ws_size,
                              hipStream_t stream)
{
    (void)in_sizes; (void)n_in; (void)out_size; (void)ws_size;
    const float* hs   = (const float*)d_in[0];
    const float* Wqa  = (const float*)d_in[1];
    const float* qlnw = (const float*)d_in[2];
    const float* Wqb  = (const float*)d_in[3];
    const float* Wkva = (const float*)d_in[4];
    const float* klnw = (const float*)d_in[5];
    const float* Wkvb = (const float*)d_in[6];
    const float* Wo   = (const float*)d_in[7];
    float* out = (float*)d_out;

    ushort_t* p = (ushort_t*)d_ws;
    ushort_t* hs16   = p; p += (size_t)S_LEN * H_DIM;
    ushort_t* WcatT  = p; p += (size_t)2176 * H_DIM;     // [Wqa^T 1536 ; Wkva^T 640] x 2048
    ushort_t* WqbT   = p; p += (size_t)3072 * Q_LORA;
    ushort_t* WkvbT  = p; p += (size_t)4096 * KV_LORA;
    ushort_t* WoT    = p; p += (size_t)H_DIM * H_DIM;
    ushort_t* cat16r = p; p += (size_t)S_LEN * 2176;     // [qa_raw | ckv_raw | kpe_raw | pad]
    ushort_t* qa16   = p; p += (size_t)S_LEN * Q_LORA;
    ushort_t* qbuf16 = p; p += (size_t)S_LEN * 3072;
    ushort_t* ckv16n = p; p += (size_t)S_LEN * KV_LORA;
    ushort_t* kpe16  = p; p += (size_t)S_LEN * D_ROPE;
    ushort_t* kv16   = p; p += (size_t)S_LEN * 4096;
    ushort_t* v16t   = p; p += (size_t)NH * D_V * S_LEN;
    ushort_t* aout16 = p; p += (size_t)S_LEN * 2048;

    // 192^-0.5 * log2(e): attention scale + exp->exp2 folded into q projection
    const float QSCALE = 0.0721687836f * 1.44269504f;

    // 1. all conversions in one launch (hs + 5 weight transposes)
    unified_conv<<<19200, 256, 0, stream>>>(
        hs, hs16, Wqa, Wkva, Wqb, Wkvb, Wo, WcatT, WqbT, WkvbT, WoT);
    // 2. cat16r = hs16 @ WcatT^T  [2048 x 2176, K=2048]  — 8-wave blocks
    mfma_gemm_bt<ushort_t><<<dim3(2176 / 128, S_LEN / 128), 512, 0, stream>>>(
        hs16, WcatT, cat16r, 2176, H_DIM);
    // 3. fused rmsnorm-q / rmsnorm-kv / rope-k
    fused_norm_ropek<<<4096 + 256, 256, 0, stream>>>(cat16r, qa16, ckv16n, kpe16, qlnw, klnw);
    // 4. grouped GEMM: qbuf16 (pre-scaled) + kv16 with fused V-transpose epilogue
    mfma_gemm_dual<<<384 + 512, 256, 0, stream>>>(
        qa16, WqbT, qbuf16, 3072, Q_LORA, 384, QSCALE,
        ckv16n, WkvbT, kv16, 4096, KV_LORA, v16t);
    // 5. attention (R10 exact: swapped-operand lane-local softmax, R5 pipeline)
    mla_attn_kernel<<<512, 256, 0, stream>>>(qbuf16, kv16, kpe16, v16t, aout16);
    // 6. out = aout16 @ WoT^T [2048 x 2048, K=2048], fp32 store — 8-wave blocks
    mfma_gemm_bt<float><<<dim3(H_DIM / 128, S_LEN / 128), 512, 0, stream>>>(
        aout16, WoT, out, H_DIM, H_DIM);
}